// Round 11
// baseline (412.399 us; speedup 1.0000x reference)
//
#include <hip/hip_runtime.h>
#include <math.h>

constexpr int kM  = 32768;
constexpr int kD  = 1024;
constexpr int kDE = 128;
constexpr int kK  = 32;
constexpr int kCap = 2048;          // candidate capacity per batch
constexpr int kLBuf = 128;          // per-block LDS candidate buffer
constexpr float kT0 = 0.20f;        // speculative threshold (fallback guards exactness)

typedef float f4 __attribute__((ext_vector_type(4)));

__device__ __forceinline__ int score_bin(float s) {
  float w = (s + 1.0f) * 128.0f;
  w = fminf(fmaxf(w, 0.0f), 255.0f);
  return (int)w;
}
__device__ __forceinline__ unsigned long long pack_key(float s, int idx) {
  unsigned u = __float_as_uint(s);
  u = (u & 0x80000000u) ? ~u : (u | 0x80000000u);
  return ((unsigned long long)u << 32) | (unsigned)(~idx);
}

// ---------------------------------------------------------------------------
// Kernel A: qproj split-K partials. grid 256 (8 slices x 32 batches), block 256.
// Also zeroes per-batch counters.
// ---------------------------------------------------------------------------
__global__ __launch_bounds__(256) void qproj_part(
    const float* __restrict__ x, const float* __restrict__ y,
    const float* __restrict__ Wqe, const float* __restrict__ Wqc,
    float* __restrict__ pq, float* __restrict__ pqc,
    unsigned* __restrict__ gcnt, unsigned* __restrict__ gflag,
    unsigned* __restrict__ gdone) {
  const int blk = blockIdx.x, t = threadIdx.x;
  const int qb = blk >> 3, slice = blk & 7;
  const int h = t >> 7, j = t & 127;
  const int S = slice * 2 + h;   // 0..15 K-subslice of concat(x,y)

  const float* srcA = (S < 8) ? (x + qb * kD + S * 128)
                              : (y + qb * kD + (S - 8) * 128);
  const float* wA = Wqe + (size_t)(S * 128) * kDE + j;
  float s0 = 0.f, s1 = 0.f, s2 = 0.f, s3 = 0.f;
#pragma unroll 8
  for (int i = 0; i < 128; i += 4) {
    s0 += srcA[i]     * wA[(size_t)(i)     * kDE];
    s1 += srcA[i + 1] * wA[(size_t)(i + 1) * kDE];
    s2 += srcA[i + 2] * wA[(size_t)(i + 2) * kDE];
    s3 += srcA[i + 3] * wA[(size_t)(i + 3) * kDE];
  }
  pq[(qb * 16 + S) * 128 + j] = (s0 + s1) + (s2 + s3);

  const float* srcB = x + qb * kD + S * 64;
  const float* wB = Wqc + (size_t)(S * 64) * kDE + j;
  float c0 = 0.f, c1 = 0.f, c2 = 0.f, c3 = 0.f;
#pragma unroll 8
  for (int i = 0; i < 64; i += 4) {
    c0 += srcB[i]     * wB[(size_t)(i)     * kDE];
    c1 += srcB[i + 1] * wB[(size_t)(i + 1) * kDE];
    c2 += srcB[i + 2] * wB[(size_t)(i + 2) * kDE];
    c3 += srcB[i + 3] * wB[(size_t)(i + 3) * kDE];
  }
  pqc[(qb * 16 + S) * 128 + j] = (c0 + c1) + (c2 + c3);

  if (slice == 0 && t == 0) { gcnt[qb] = 0u; gflag[qb] = 0u; gdone[qb] = 0u; }
}

// ---------------------------------------------------------------------------
// Kernel B: scores streaming (R7 hot loop) + last-block-done finish.
// grid (64 chunks, 32 batches), block 256. 64 blocks/batch -> finisher is the
// block whose fetch_add returns 63.
// ---------------------------------------------------------------------------
__global__ __launch_bounds__(256) void scores_finish(
    const float* __restrict__ emK, const float* __restrict__ emV,
    const float* __restrict__ emS,
    const float* __restrict__ pq, const float* __restrict__ pqc,
    const float* __restrict__ bqe, const float* __restrict__ bqc,
    float* __restrict__ sc,
    unsigned* __restrict__ gcnt, unsigned long long* __restrict__ gcand,
    unsigned* __restrict__ gflag, unsigned* __restrict__ gdone,
    const float* __restrict__ lng, const float* __restrict__ lnb,
    const float* __restrict__ f1w, const float* __restrict__ f1b,
    const float* __restrict__ f2w, const float* __restrict__ f2b,
    const float* __restrict__ Wo, const float* __restrict__ Wob,
    float* __restrict__ out) {
  const int b = blockIdx.y, chunk = blockIdx.x;
  const int t = threadIdx.x;
  const int wave = t >> 6, lane = t & 63;
  const int half = lane >> 5, l32 = lane & 31;

  __shared__ float ql[128];
  __shared__ float redn[2];
  __shared__ unsigned lcnt, lbase;
  __shared__ unsigned long long lbuf[kLBuf];
  __shared__ unsigned doneS;

  if (t == 0) lcnt = 0u;

  // ---- per-block q reduce from partials (L2-hot, 16x128) + normalize
  float aq = 0.f;
  if (t < 128) {
    aq = bqe[t];
#pragma unroll
    for (int S2 = 0; S2 < 16; ++S2) aq += pq[(b * 16 + S2) * 128 + t];
    float sq = aq * aq;
#pragma unroll
    for (int m = 1; m < 64; m <<= 1) sq += __shfl_xor(sq, m);
    if ((t & 63) == 0) redn[t >> 6] = sq;
  }
  __syncthreads();
  if (t < 128) ql[t] = aq * (1.f / sqrtf(redn[0] + redn[1] + 1e-12f));
  __syncthreads();

  // ---- scores hot loop (R7's proven 93us/5.54TB/s loop)
  {
    const float4 qf = *reinterpret_cast<const float4*>(&ql[l32 * 4]);
    const int rowbase = chunk * 512 + wave * 128;
    const float* Kb = emK + (size_t)b * kM * kDE;
    const float* Sb = emS + (size_t)b * kM;
    float* scb = sc + (size_t)b * kM;

    for (int it = 0; it < 8; ++it) {
      const int A = rowbase + it * 16 + half * 8;
      const float* p = Kb + (size_t)A * kDE + l32 * 4;
      const f4 k0 = __builtin_nontemporal_load((const f4*)(p));
      const f4 k1 = __builtin_nontemporal_load((const f4*)(p + kDE));
      const f4 k2 = __builtin_nontemporal_load((const f4*)(p + 2 * kDE));
      const f4 k3 = __builtin_nontemporal_load((const f4*)(p + 3 * kDE));
      const f4 k4 = __builtin_nontemporal_load((const f4*)(p + 4 * kDE));
      const f4 k5 = __builtin_nontemporal_load((const f4*)(p + 5 * kDE));
      const f4 k6 = __builtin_nontemporal_load((const f4*)(p + 6 * kDE));
      const f4 k7 = __builtin_nontemporal_load((const f4*)(p + 7 * kDE));

      float d0 = fmaf(k0.w, qf.w, fmaf(k0.z, qf.z, fmaf(k0.y, qf.y, k0.x * qf.x)));
      float d1 = fmaf(k1.w, qf.w, fmaf(k1.z, qf.z, fmaf(k1.y, qf.y, k1.x * qf.x)));
      float d2 = fmaf(k2.w, qf.w, fmaf(k2.z, qf.z, fmaf(k2.y, qf.y, k2.x * qf.x)));
      float d3 = fmaf(k3.w, qf.w, fmaf(k3.z, qf.z, fmaf(k3.y, qf.y, k3.x * qf.x)));
      float d4 = fmaf(k4.w, qf.w, fmaf(k4.z, qf.z, fmaf(k4.y, qf.y, k4.x * qf.x)));
      float d5 = fmaf(k5.w, qf.w, fmaf(k5.z, qf.z, fmaf(k5.y, qf.y, k5.x * qf.x)));
      float d6 = fmaf(k6.w, qf.w, fmaf(k6.z, qf.z, fmaf(k6.y, qf.y, k6.x * qf.x)));
      float d7 = fmaf(k7.w, qf.w, fmaf(k7.z, qf.z, fmaf(k7.y, qf.y, k7.x * qf.x)));

      // folded butterfly: lane 4k ends with total for row A+k
      d0 += __shfl_xor(d0, 16); d1 += __shfl_xor(d1, 16);
      d2 += __shfl_xor(d2, 16); d3 += __shfl_xor(d3, 16);
      d4 += __shfl_xor(d4, 16); d5 += __shfl_xor(d5, 16);
      d6 += __shfl_xor(d6, 16); d7 += __shfl_xor(d7, 16);
      float w0 = (l32 & 16) ? d4 : d0;
      float w1 = (l32 & 16) ? d5 : d1;
      float w2 = (l32 & 16) ? d6 : d2;
      float w3 = (l32 & 16) ? d7 : d3;
      w0 += __shfl_xor(w0, 8); w1 += __shfl_xor(w1, 8);
      w2 += __shfl_xor(w2, 8); w3 += __shfl_xor(w3, 8);
      float u0 = (l32 & 8) ? w2 : w0;
      float u1 = (l32 & 8) ? w3 : w1;
      u0 += __shfl_xor(u0, 4); u1 += __shfl_xor(u1, 4);
      float z = (l32 & 4) ? u1 : u0;
      z += __shfl_xor(z, 2);
      z += __shfl_xor(z, 1);

      const float sv = Sb[A + (l32 >> 2)];
      if ((l32 & 3) == 0) {
        const int row = A + (l32 >> 2);
        const float val = (sv > 0.f) ? z : -INFINITY;
        __builtin_nontemporal_store(val, &scb[row]);
        if (val >= kT0) {
          const unsigned pos = atomicAdd(&lcnt, 1u);   // LDS atomic only
          if (pos < (unsigned)kLBuf) lbuf[pos] = pack_key(val, row);
        }
      }
    }
  }
  __syncthreads();

  // ---- one flush per block
  const unsigned c = min(lcnt, (unsigned)kLBuf);
  if (t == 0) {
    lbase = atomicAdd(&gcnt[b], c);
    if (lcnt > (unsigned)kLBuf) atomicOr(&gflag[b], 1u);
  }
  __syncthreads();
  for (unsigned i = t; i < c; i += 256) {
    const unsigned pos = lbase + i;
    if (pos < (unsigned)kCap) gcand[(size_t)b * kCap + pos] = lbuf[i];
  }
  __syncthreads();

  // ---- completion: LAST of the 64 blocks for batch b runs finish (no spin)
  if (t == 0)
    doneS = __hip_atomic_fetch_add(&gdone[b], 1u, __ATOMIC_ACQ_REL,
                                   __HIP_MEMORY_SCOPE_AGENT);
  __syncthreads();
  if (doneS != 63u) return;   // 64 blocks per batch (grid.x = 64)

  // ======================= finish for batch b =============================
  __shared__ float qcl[128];
  __shared__ float outvS[32];
  __shared__ int outiS[32];
  __shared__ float wgt[32];
  __shared__ float hS[128];
  __shared__ float y1S[512];
  __shared__ float p2S[2][128];
  __shared__ float o2S[128];
  __shared__ float redA[2], redB[2];
  __shared__ int nS;

  if (t < 128) {
    float cc = bqc[t];
#pragma unroll
    for (int S2 = 0; S2 < 16; ++S2) cc += pqc[(b * 16 + S2) * 128 + t];
    qcl[t] = cc;
  }
  if (t < 32) { outvS[t] = -INFINITY; outiS[t] = 0; }

  const unsigned cnt =
      __hip_atomic_load(&gcnt[b], __ATOMIC_ACQUIRE, __HIP_MEMORY_SCOPE_AGENT);
  const unsigned flg =
      __hip_atomic_load(&gflag[b], __ATOMIC_ACQUIRE, __HIP_MEMORY_SCOPE_AGENT);
  unsigned long long* cand = gcand + (size_t)b * kCap;
  const float* scb = sc + (size_t)b * kM;

  if (flg == 0u && cnt >= 32u && cnt <= (unsigned)kCap) {
    if (t == 0) nS = (int)cnt;
    __syncthreads();
  } else {
    // exact fallback: histogram threshold over full score array, compact to gcand
    __shared__ unsigned shist[256];
    __shared__ int Bsh;
    __shared__ unsigned cnt2;
    shist[t] = 0u;
    if (t == 0) { Bsh = 0; cnt2 = 0u; }
    __syncthreads();
    for (int i = t; i < kM; i += 256)
      atomicAdd(&shist[score_bin(scb[i])], 1u);
    __syncthreads();
    for (int off = 1; off < 256; off <<= 1) {
      unsigned v = shist[t];
      if (t + off < 256) v += shist[t + off];
      __syncthreads();
      shist[t] = v;
      __syncthreads();
    }
    if (shist[t] >= 32u) atomicMax(&Bsh, t);
    __syncthreads();
    const int B = Bsh;
    for (int i = t; i < kM; i += 256) {
      const float s = scb[i];
      if (score_bin(s) >= B) {
        const unsigned pos = atomicAdd(&cnt2, 1u);
        if (pos < (unsigned)kCap) cand[pos] = pack_key(s, i);
      }
    }
    __syncthreads();
    if (t == 0) nS = (int)min(cnt2, (unsigned)kCap);
    __syncthreads();
  }
  const int n = nS;

  // rank-select straight from gcand (L2-hot): rank<32 -> output slot
  for (int base = 0; base < n; base += 256) {
    const bool valid = (base + t) < n;
    unsigned long long key = 0ull;
    if (valid) key = cand[base + t];
    int rank = 0;
    for (int i = 0; i < n; ++i) rank += (cand[i] > key);
    if (valid && rank < 32) {
      const unsigned mono = (unsigned)(key >> 32);
      const unsigned u = (mono & 0x80000000u) ? (mono & 0x7fffffffu) : ~mono;
      outvS[rank] = __uint_as_float(u);
      outiS[rank] = (int)(~(unsigned)key);
    }
  }
  __syncthreads();

  // attention logits: 4 waves x 8 rows, V rows direct from global
  const float* Vb = emV + (size_t)b * kM * kDE;
  {
    const float qa = qcl[2 * lane], qb2 = qcl[2 * lane + 1];
#pragma unroll
    for (int kk = 0; kk < 8; ++kk) {
      const int k = wave * 8 + kk;
      const float2 vv =
          *reinterpret_cast<const float2*>(&Vb[(size_t)outiS[k] * kDE + 2 * lane]);
      float p = vv.x * qa + vv.y * qb2;
#pragma unroll
      for (int m = 1; m < 64; m <<= 1) p += __shfl_xor(p, m);
      if (lane == 0) {
        const float tv = outvS[k];
        wgt[k] = (tv == -INFINITY) ? -INFINITY : fmaf(p, 0.08838834764831845f, tv);
      }
    }
  }
  __syncthreads();

  // softmax over 32 logits (nan_to_num semantics)
  if (t < 32) {
    const float lg = wgt[t];
    float mx = lg;
#pragma unroll
    for (int m = 1; m < 32; m <<= 1) mx = fmaxf(mx, __shfl_xor(mx, m));
    float e = (mx == -INFINITY || lg == -INFINITY) ? 0.f : __expf(lg - mx);
    float ssum = e;
#pragma unroll
    for (int m = 1; m < 32; m <<= 1) ssum += __shfl_xor(ssum, m);
    wgt[t] = (ssum > 0.f) ? e / ssum : 0.f;
  }
  __syncthreads();

  // out = sum_k w_k V_k (t<128, V L2-hot), then LayerNorm
  float od = 0.f;
  if (t < 128) {
#pragma unroll 8
    for (int k = 0; k < 32; ++k) od += wgt[k] * Vb[(size_t)outiS[k] * kDE + t];
    float s1 = od, s2 = od * od;
#pragma unroll
    for (int m = 1; m < 64; m <<= 1) {
      s1 += __shfl_xor(s1, m);
      s2 += __shfl_xor(s2, m);
    }
    if ((t & 63) == 0) { redA[t >> 6] = s1; redB[t >> 6] = s2; }
  }
  __syncthreads();
  const float mu = (redA[0] + redA[1]) * (1.f / 128.f);
  const float var = (redB[0] + redB[1]) * (1.f / 128.f) - mu * mu;
  const float rstd = 1.f / sqrtf(var + 1e-5f);
  if (t < 128) hS[t] = (od - mu) * rstd * lng[t] + lnb[t];
  __syncthreads();

  // FFN1 + exact GELU: 512 outputs, 2 per thread
#pragma unroll
  for (int jj = 0; jj < 2; ++jj) {
    const int col = t + jj * 256;
    float acc = f1b[col];
#pragma unroll 8
    for (int d = 0; d < 128; ++d) acc += hS[d] * f1w[(size_t)d * 512 + col];
    y1S[col] = 0.5f * acc * (1.f + erff(acc * 0.7071067811865476f));
  }
  __syncthreads();

  // FFN2 split-K (2 halves of 256)
  {
    const int g = t >> 7, col = t & 127;
    float acc = 0.f;
#pragma unroll 8
    for (int jj = 0; jj < 256; ++jj)
      acc += y1S[g * 256 + jj] * f2w[(size_t)(g * 256 + jj) * 128 + col];
    p2S[g][col] = acc;
  }
  __syncthreads();
  if (t < 128) o2S[t] = od + f2b[t] + p2S[0][t] + p2S[1][t];
  __syncthreads();

  // final projection: 1024 outputs, 4 per thread
  float a0 = Wob[t], a1 = Wob[t + 256], a2 = Wob[t + 512], a3 = Wob[t + 768];
#pragma unroll 4
  for (int d = 0; d < 128; ++d) {
    const float hv = o2S[d];
    a0 += hv * Wo[(size_t)d * kD + t];
    a1 += hv * Wo[(size_t)d * kD + t + 256];
    a2 += hv * Wo[(size_t)d * kD + t + 512];
    a3 += hv * Wo[(size_t)d * kD + t + 768];
  }
  float* ob = out + (size_t)b * kD;
  ob[t] = a0;
  ob[t + 256] = a1;
  ob[t + 512] = a2;
  ob[t + 768] = a3;
}

// ---------------------------------------------------------------------------
extern "C" void kernel_launch(void* const* d_in, const int* in_sizes, int n_in,
                              void* d_out, int out_size, void* d_ws, size_t ws_size,
                              hipStream_t stream) {
  const float* x   = (const float*)d_in[0];
  const float* y   = (const float*)d_in[1];
  const float* emK = (const float*)d_in[2];
  const float* emV = (const float*)d_in[3];
  const float* emS = (const float*)d_in[4];
  const float* Wqe = (const float*)d_in[5];
  const float* bqe = (const float*)d_in[6];
  const float* Wqc = (const float*)d_in[7];
  const float* bqc = (const float*)d_in[8];
  const float* Wo  = (const float*)d_in[9];
  const float* Wob = (const float*)d_in[10];
  const float* lng = (const float*)d_in[11];
  const float* lnb = (const float*)d_in[12];
  const float* f1w = (const float*)d_in[13];
  const float* f1b = (const float*)d_in[14];
  const float* f2w = (const float*)d_in[15];
  const float* f2b = (const float*)d_in[16];
  float* out = (float*)d_out;

  float* ws = (float*)d_ws;
  float* pq  = ws;                                  // 32*16*128 = 65536 f
  float* pqc = ws + 65536;                          // 65536 f
  float* sc  = ws + 131072;                         // 32*32768 = 1048576 f
  unsigned long long* gcand =
      (unsigned long long*)(ws + 1179648);          // 32*2048 u64 = 131072 f
  unsigned* gcnt  = (unsigned*)(ws + 1310720);      // 32
  unsigned* gflag = gcnt + 32;                      // 32
  unsigned* gdone = gflag + 32;                     // 32

  hipLaunchKernelGGL(qproj_part, dim3(256), dim3(256), 0, stream,
                     x, y, Wqe, Wqc, pq, pqc, gcnt, gflag, gdone);
  hipLaunchKernelGGL(scores_finish, dim3(64, 32), dim3(256), 0, stream,
                     emK, emV, emS, pq, pqc, bqe, bqc, sc,
                     gcnt, gcand, gflag, gdone,
                     lng, lnb, f1w, f1b, f2w, f2b, Wo, Wob, out);
}

// Round 12
// 149.064 us; speedup vs baseline: 2.7666x; 2.7666x over previous
//
#include <hip/hip_runtime.h>
#include <math.h>

constexpr int kM  = 32768;
constexpr int kD  = 1024;
constexpr int kDE = 128;
constexpr int kK  = 32;
constexpr int kCap = 2048;          // candidate capacity per batch
constexpr int kLBuf = 128;          // per-block LDS candidate buffer
constexpr float kT0 = 0.20f;        // speculative threshold (fallback guards exactness)

typedef float f4 __attribute__((ext_vector_type(4)));

__device__ __forceinline__ int score_bin(float s) {
  float w = (s + 1.0f) * 128.0f;
  w = fminf(fmaxf(w, 0.0f), 255.0f);
  return (int)w;
}
__device__ __forceinline__ unsigned long long pack_key(float s, int idx) {
  unsigned u = __float_as_uint(s);
  u = (u & 0x80000000u) ? ~u : (u | 0x80000000u);
  return ((unsigned long long)u << 32) | (unsigned)(~idx);
}

// ---------------------------------------------------------------------------
// Kernel A: qproj split-K partials + last-of-8 in-kernel reduce.
// grid 256 (32 batches x 8 slices), block 256. gdone zeroed by hipMemsetAsync.
// ---------------------------------------------------------------------------
__global__ __launch_bounds__(256) void qproj_fused(
    const float* __restrict__ x, const float* __restrict__ y,
    const float* __restrict__ Wqe, const float* __restrict__ bqe,
    const float* __restrict__ Wqc, const float* __restrict__ bqc,
    float* __restrict__ pq, float* __restrict__ pqc,
    float* __restrict__ q, float* __restrict__ qc,
    unsigned* __restrict__ gdone) {
  const int blk = blockIdx.x, t = threadIdx.x;
  const int qb = blk >> 3, slice = blk & 7;
  const int h = t >> 7, j = t & 127;
  const int S = slice * 2 + h;   // 0..15 K-subslice of concat(x,y)

  const float* srcA = (S < 8) ? (x + qb * kD + S * 128)
                              : (y + qb * kD + (S - 8) * 128);
  const float* wA = Wqe + (size_t)(S * 128) * kDE + j;
  float s0 = 0.f, s1 = 0.f, s2 = 0.f, s3 = 0.f;
#pragma unroll 8
  for (int i = 0; i < 128; i += 4) {
    s0 += srcA[i]     * wA[(size_t)(i)     * kDE];
    s1 += srcA[i + 1] * wA[(size_t)(i + 1) * kDE];
    s2 += srcA[i + 2] * wA[(size_t)(i + 2) * kDE];
    s3 += srcA[i + 3] * wA[(size_t)(i + 3) * kDE];
  }
  pq[(qb * 16 + S) * 128 + j] = (s0 + s1) + (s2 + s3);

  const float* srcB = x + qb * kD + S * 64;
  const float* wB = Wqc + (size_t)(S * 64) * kDE + j;
  float c0 = 0.f, c1 = 0.f, c2 = 0.f, c3 = 0.f;
#pragma unroll 8
  for (int i = 0; i < 64; i += 4) {
    c0 += srcB[i]     * wB[(size_t)(i)     * kDE];
    c1 += srcB[i + 1] * wB[(size_t)(i + 1) * kDE];
    c2 += srcB[i + 2] * wB[(size_t)(i + 2) * kDE];
    c3 += srcB[i + 3] * wB[(size_t)(i + 3) * kDE];
  }
  pqc[(qb * 16 + S) * 128 + j] = (c0 + c1) + (c2 + c3);

  __syncthreads();
  __shared__ unsigned doneS;
  if (t == 0)
    doneS = __hip_atomic_fetch_add(&gdone[qb], 1u, __ATOMIC_ACQ_REL,
                                   __HIP_MEMORY_SCOPE_AGENT);
  __syncthreads();
  if (doneS != 7u) return;   // last of 8 blocks for this batch reduces

  float a = 0.f, c = 0.f;
  if (t < 128) {
    a = bqe[t];
    c = bqc[t];
#pragma unroll
    for (int S2 = 0; S2 < 16; ++S2) {
      a += pq[(qb * 16 + S2) * 128 + t];
      c += pqc[(qb * 16 + S2) * 128 + t];
    }
  }
  __shared__ float redn[2];
  float sq = a * a;
#pragma unroll
  for (int m = 1; m < 64; m <<= 1) sq += __shfl_xor(sq, m);
  if (t == 0 || t == 64) redn[t >> 6] = sq;
  __syncthreads();
  if (t < 128) {
    const float inv = 1.f / sqrtf(redn[0] + redn[1] + 1e-12f);
    q[qb * kDE + t] = a * inv;
    qc[qb * kDE + t] = c;
  }
}

// ---------------------------------------------------------------------------
// Kernel B: scores (R7-verbatim; proven 93us / 5.5 TB/s effective).
// grid (64 chunks, 32 batches), block 256 (4 waves).
// ---------------------------------------------------------------------------
__global__ __launch_bounds__(256) void scores_kernel(
    const float* __restrict__ emK, const float* __restrict__ emS,
    const float* __restrict__ q, float* __restrict__ sc,
    unsigned int* __restrict__ gcnt, unsigned long long* __restrict__ gcand,
    unsigned int* __restrict__ gflag) {
  const int b = blockIdx.y, chunk = blockIdx.x;
  const int wave = threadIdx.x >> 6;
  const int lane = threadIdx.x & 63;
  const int half = lane >> 5;
  const int l32 = lane & 31;

  __shared__ unsigned int lcnt;
  __shared__ unsigned int lbase;
  __shared__ unsigned long long lbuf[kLBuf];
  if (threadIdx.x == 0) lcnt = 0u;
  __syncthreads();

  const float4 qf = *reinterpret_cast<const float4*>(q + b * kDE + l32 * 4);
  const int rowbase = chunk * 512 + wave * 128;
  const float* Kb = emK + (size_t)b * kM * kDE;
  const float* Sb = emS + (size_t)b * kM;
  float* scb = sc + (size_t)b * kM;

  for (int it = 0; it < 8; ++it) {
    const int A = rowbase + it * 16 + half * 8;
    const float* p = Kb + (size_t)A * kDE + l32 * 4;
    const f4 k0 = __builtin_nontemporal_load((const f4*)(p));
    const f4 k1 = __builtin_nontemporal_load((const f4*)(p + kDE));
    const f4 k2 = __builtin_nontemporal_load((const f4*)(p + 2 * kDE));
    const f4 k3 = __builtin_nontemporal_load((const f4*)(p + 3 * kDE));
    const f4 k4 = __builtin_nontemporal_load((const f4*)(p + 4 * kDE));
    const f4 k5 = __builtin_nontemporal_load((const f4*)(p + 5 * kDE));
    const f4 k6 = __builtin_nontemporal_load((const f4*)(p + 6 * kDE));
    const f4 k7 = __builtin_nontemporal_load((const f4*)(p + 7 * kDE));

    float d0 = fmaf(k0.w, qf.w, fmaf(k0.z, qf.z, fmaf(k0.y, qf.y, k0.x * qf.x)));
    float d1 = fmaf(k1.w, qf.w, fmaf(k1.z, qf.z, fmaf(k1.y, qf.y, k1.x * qf.x)));
    float d2 = fmaf(k2.w, qf.w, fmaf(k2.z, qf.z, fmaf(k2.y, qf.y, k2.x * qf.x)));
    float d3 = fmaf(k3.w, qf.w, fmaf(k3.z, qf.z, fmaf(k3.y, qf.y, k3.x * qf.x)));
    float d4 = fmaf(k4.w, qf.w, fmaf(k4.z, qf.z, fmaf(k4.y, qf.y, k4.x * qf.x)));
    float d5 = fmaf(k5.w, qf.w, fmaf(k5.z, qf.z, fmaf(k5.y, qf.y, k5.x * qf.x)));
    float d6 = fmaf(k6.w, qf.w, fmaf(k6.z, qf.z, fmaf(k6.y, qf.y, k6.x * qf.x)));
    float d7 = fmaf(k7.w, qf.w, fmaf(k7.z, qf.z, fmaf(k7.y, qf.y, k7.x * qf.x)));

    // folded butterfly reduce: lane 4k ends with total for row A+k
    d0 += __shfl_xor(d0, 16); d1 += __shfl_xor(d1, 16);
    d2 += __shfl_xor(d2, 16); d3 += __shfl_xor(d3, 16);
    d4 += __shfl_xor(d4, 16); d5 += __shfl_xor(d5, 16);
    d6 += __shfl_xor(d6, 16); d7 += __shfl_xor(d7, 16);
    float w0 = (l32 & 16) ? d4 : d0;
    float w1 = (l32 & 16) ? d5 : d1;
    float w2 = (l32 & 16) ? d6 : d2;
    float w3 = (l32 & 16) ? d7 : d3;
    w0 += __shfl_xor(w0, 8); w1 += __shfl_xor(w1, 8);
    w2 += __shfl_xor(w2, 8); w3 += __shfl_xor(w3, 8);
    float u0 = (l32 & 8) ? w2 : w0;
    float u1 = (l32 & 8) ? w3 : w1;
    u0 += __shfl_xor(u0, 4); u1 += __shfl_xor(u1, 4);
    float z = (l32 & 4) ? u1 : u0;
    z += __shfl_xor(z, 2);
    z += __shfl_xor(z, 1);

    const float sv = Sb[A + (l32 >> 2)];
    if ((l32 & 3) == 0) {
      const int row = A + (l32 >> 2);
      const float val = (sv > 0.f) ? z : -INFINITY;
      __builtin_nontemporal_store(val, &scb[row]);
      if (val >= kT0) {
        const unsigned pos = atomicAdd(&lcnt, 1u);   // LDS atomic only
        if (pos < (unsigned)kLBuf) lbuf[pos] = pack_key(val, row);
      }
    }
  }
  __syncthreads();

  // one flush per block
  const unsigned c = min(lcnt, (unsigned)kLBuf);
  if (threadIdx.x == 0) {
    lbase = atomicAdd(&gcnt[b], c);
    if (lcnt > (unsigned)kLBuf) atomicOr(&gflag[b], 1u);
  }
  __syncthreads();
  const unsigned base = lbase;
  for (unsigned i = threadIdx.x; i < c; i += 256) {
    const unsigned pos = base + i;
    if (pos < (unsigned)kCap) gcand[(size_t)b * kCap + pos] = lbuf[i];
  }
}

// ---------------------------------------------------------------------------
// Kernel C: finish (R7-verbatim). grid 32, block 512.
// ---------------------------------------------------------------------------
__global__ __launch_bounds__(512) void finish_kernel(
    const float* __restrict__ sc, const unsigned int* __restrict__ gcnt,
    const unsigned long long* __restrict__ gcand,
    const unsigned int* __restrict__ gflag,
    const float* __restrict__ emV, const float* __restrict__ qc,
    const float* __restrict__ lng, const float* __restrict__ lnb,
    const float* __restrict__ f1w, const float* __restrict__ f1b,
    const float* __restrict__ f2w, const float* __restrict__ f2b,
    const float* __restrict__ Wo, const float* __restrict__ Wob,
    float* __restrict__ out) {
  const int b = blockIdx.x, t = threadIdx.x;
  const int wave = t >> 6, lane = t & 63;

  __shared__ unsigned long long ck[kCap];
  __shared__ int nS;
  __shared__ float outvS[32];
  __shared__ int outiS[32];
  __shared__ float Vt[32][128];
  __shared__ float qcl[128];
  __shared__ float wgt[32];
  __shared__ float hS[128];
  __shared__ float y1S[512];
  __shared__ float p2S[4][128];
  __shared__ float o2S[128];
  __shared__ float redA[2];
  __shared__ float redB[2];

  const unsigned cnt = gcnt[b];
  const unsigned flag = gflag[b];
  const float* scb = sc + (size_t)b * kM;
  if (t < 128) qcl[t] = qc[b * kDE + t];
  if (t < 32) { outvS[t] = -INFINITY; outiS[t] = 0; }

  if (flag == 0u && cnt >= 32u && cnt <= (unsigned)kCap) {
    for (unsigned i = t; i < cnt; i += 512)
      ck[i] = gcand[(size_t)b * kCap + i];
    if (t == 0) nS = (int)cnt;
  } else {
    __shared__ unsigned int shist[256];
    __shared__ int Bsh;
    __shared__ unsigned int cnt2;
    if (t < 256) shist[t] = 0u;
    if (t == 0) { Bsh = 0; cnt2 = 0u; }
    __syncthreads();
    for (int i = t; i < kM; i += 512)
      atomicAdd(&shist[score_bin(scb[i])], 1u);
    __syncthreads();
    for (int off = 1; off < 256; off <<= 1) {
      unsigned v = 0;
      if (t < 256) {
        v = shist[t];
        if (t + off < 256) v += shist[t + off];
      }
      __syncthreads();
      if (t < 256) shist[t] = v;
      __syncthreads();
    }
    if (t < 256 && shist[t] >= 32u) atomicMax(&Bsh, t);
    __syncthreads();
    const int B = Bsh;
    for (int i = t; i < kM; i += 512) {
      const float s = scb[i];
      if (score_bin(s) >= B) {
        const unsigned pos = atomicAdd(&cnt2, 1u);
        if (pos < (unsigned)kCap) ck[pos] = pack_key(s, i);
      }
    }
    __syncthreads();
    if (t == 0) nS = (int)min(cnt2, (unsigned)kCap);
  }
  __syncthreads();
  const int n = nS;

  unsigned long long mykey0 = 0, mykey1 = 0, mykey2 = 0, mykey3 = 0;
  if (t < n) mykey0 = ck[t];
  if (t + 512 < n) mykey1 = ck[t + 512];
  if (t + 1024 < n) mykey2 = ck[t + 1024];
  if (t + 1536 < n) mykey3 = ck[t + 1536];
  int r0 = 0, r1 = 0, r2 = 0, r3 = 0;
  for (int i = 0; i < n; ++i) {
    const unsigned long long o = ck[i];
    r0 += (o > mykey0);
    r1 += (o > mykey1);
    r2 += (o > mykey2);
    r3 += (o > mykey3);
  }
  auto emit = [&](unsigned long long key, int rank, int slot) {
    if (slot < n && rank < 32) {
      const unsigned mono = (unsigned)(key >> 32);
      const unsigned u = (mono & 0x80000000u) ? (mono & 0x7fffffffu) : ~mono;
      outvS[rank] = __uint_as_float(u);
      outiS[rank] = (int)(~(unsigned)key);
    }
  };
  emit(mykey0, r0, t);
  emit(mykey1, r1, t + 512);
  emit(mykey2, r2, t + 1024);
  emit(mykey3, r3, t + 1536);
  __syncthreads();

  const float* Vb = emV + (size_t)b * kM * kDE;
#pragma unroll
  for (int e = t; e < 32 * 128; e += 512) {
    const int r = e >> 7, ccol = e & 127;
    Vt[r][ccol] = Vb[(size_t)outiS[r] * kDE + ccol];
  }
  __syncthreads();

#pragma unroll
  for (int kk2 = 0; kk2 < 4; ++kk2) {
    const int k = wave * 4 + kk2;
    float p = Vt[k][2 * lane] * qcl[2 * lane] + Vt[k][2 * lane + 1] * qcl[2 * lane + 1];
#pragma unroll
    for (int m = 1; m < 64; m <<= 1) p += __shfl_xor(p, m);
    if (lane == 0) {
      const float tv = outvS[k];
      wgt[k] = (tv == -INFINITY) ? -INFINITY : fmaf(p, 0.08838834764831845f, tv);
    }
  }
  __syncthreads();

  if (t < 32) {
    const float lg = wgt[t];
    float mx = lg;
#pragma unroll
    for (int m = 1; m < 32; m <<= 1) mx = fmaxf(mx, __shfl_xor(mx, m));
    float e = (mx == -INFINITY || lg == -INFINITY) ? 0.f : __expf(lg - mx);
    float ssum = e;
#pragma unroll
    for (int m = 1; m < 32; m <<= 1) ssum += __shfl_xor(ssum, m);
    wgt[t] = (ssum > 0.f) ? e / ssum : 0.f;
  }
  __syncthreads();

  float od = 0.f;
  if (t < 128) {
#pragma unroll 8
    for (int k = 0; k < 32; ++k) od += wgt[k] * Vt[k][t];
  }
  float s1 = (t < 128) ? od : 0.f;
  float s2 = (t < 128) ? od * od : 0.f;
#pragma unroll
  for (int m = 1; m < 64; m <<= 1) {
    s1 += __shfl_xor(s1, m);
    s2 += __shfl_xor(s2, m);
  }
  if (lane == 0 && wave < 2) { redA[wave] = s1; redB[wave] = s2; }
  __syncthreads();
  const float sum1 = redA[0] + redA[1];
  const float sum2 = redB[0] + redB[1];
  const float mu = sum1 * (1.f / 128.f);
  const float var = sum2 * (1.f / 128.f) - mu * mu;
  const float rstd = 1.f / sqrtf(var + 1e-5f);
  if (t < 128) hS[t] = (od - mu) * rstd * lng[t] + lnb[t];
  __syncthreads();

  {
    float acc = f1b[t];
#pragma unroll 8
    for (int d = 0; d < 128; ++d) acc += hS[d] * f1w[(size_t)d * 512 + t];
    y1S[t] = 0.5f * acc * (1.f + erff(acc * 0.7071067811865476f));
  }
  __syncthreads();

  {
    const int g = t >> 7, ccol = t & 127;
    float acc = 0.f;
#pragma unroll 8
    for (int jj = 0; jj < 128; ++jj)
      acc += y1S[g * 128 + jj] * f2w[(size_t)(g * 128 + jj) * 128 + ccol];
    p2S[g][ccol] = acc;
  }
  __syncthreads();
  if (t < 128)
    o2S[t] = od + f2b[t] + ((p2S[0][t] + p2S[1][t]) + (p2S[2][t] + p2S[3][t]));
  __syncthreads();

  float acc0 = Wob[t], acc1 = Wob[t + 512];
#pragma unroll 8
  for (int d = 0; d < 128; ++d) {
    const float hv = o2S[d];
    acc0 += hv * Wo[(size_t)d * kD + t];
    acc1 += hv * Wo[(size_t)d * kD + t + 512];
  }
  out[(size_t)b * kD + t] = acc0;
  out[(size_t)b * kD + t + 512] = acc1;
}

// ---------------------------------------------------------------------------
extern "C" void kernel_launch(void* const* d_in, const int* in_sizes, int n_in,
                              void* d_out, int out_size, void* d_ws, size_t ws_size,
                              hipStream_t stream) {
  const float* x   = (const float*)d_in[0];
  const float* y   = (const float*)d_in[1];
  const float* emK = (const float*)d_in[2];
  const float* emV = (const float*)d_in[3];
  const float* emS = (const float*)d_in[4];
  const float* Wqe = (const float*)d_in[5];
  const float* bqe = (const float*)d_in[6];
  const float* Wqc = (const float*)d_in[7];
  const float* bqc = (const float*)d_in[8];
  const float* Wo  = (const float*)d_in[9];
  const float* Wob = (const float*)d_in[10];
  const float* lng = (const float*)d_in[11];
  const float* lnb = (const float*)d_in[12];
  const float* f1w = (const float*)d_in[13];
  const float* f1b = (const float*)d_in[14];
  const float* f2w = (const float*)d_in[15];
  const float* f2b = (const float*)d_in[16];
  float* out = (float*)d_out;

  float* ws = (float*)d_ws;
  float* pq  = ws;                                  // 65536 f
  float* pqc = ws + 65536;                          // 65536 f
  float* q   = ws + 131072;                         // 4096 f
  float* qc  = ws + 135168;                         // 4096 f
  float* sc  = ws + 139264;                         // 1048576 f
  unsigned* meta = (unsigned*)(ws + 1187840);       // 96 u32 (gcnt|gflag|gdone)
  unsigned* gcnt  = meta;
  unsigned* gflag = meta + 32;
  unsigned* gdone = meta + 64;
  unsigned long long* gcand =
      (unsigned long long*)(ws + 1187968);          // 32*2048 u64 (8B-aligned)

  hipMemsetAsync(meta, 0, 96 * sizeof(unsigned), stream);
  hipLaunchKernelGGL(qproj_fused, dim3(256), dim3(256), 0, stream,
                     x, y, Wqe, bqe, Wqc, bqc, pq, pqc, q, qc, gdone);
  hipLaunchKernelGGL(scores_kernel, dim3(64, 32), dim3(256), 0, stream,
                     emK, emS, q, sc, gcnt, gcand, gflag);
  hipLaunchKernelGGL(finish_kernel, dim3(32), dim3(512), 0, stream,
                     sc, gcnt, gcand, gflag, emV, qc, lng, lnb,
                     f1w, f1b, f2w, f2b, Wo, Wob, out);
}

// Round 13
// 138.932 us; speedup vs baseline: 2.9683x; 1.0729x over previous
//
#include <hip/hip_runtime.h>
#include <math.h>

constexpr int kM  = 32768;
constexpr int kD  = 1024;
constexpr int kDE = 128;
constexpr int kK  = 32;
constexpr int kCap = 2048;          // candidate capacity per batch
constexpr int kLBuf = 128;          // per-block LDS candidate buffer
constexpr float kT0 = 0.20f;        // speculative threshold (fallback guards exactness)

typedef float f4 __attribute__((ext_vector_type(4)));

__device__ __forceinline__ int score_bin(float s) {
  float w = (s + 1.0f) * 128.0f;
  w = fminf(fmaxf(w, 0.0f), 255.0f);
  return (int)w;
}
__device__ __forceinline__ unsigned long long pack_key(float s, int idx) {
  unsigned u = __float_as_uint(s);
  u = (u & 0x80000000u) ? ~u : (u | 0x80000000u);
  return ((unsigned long long)u << 32) | (unsigned)(~idx);
}

// ---------------------------------------------------------------------------
// Kernel A: qproj split-K partials ONLY (no completion logic). Zeroes the
// per-batch counters consumed by later kernels. grid 256 (32 batches x 8
// slices), block 256.
// ---------------------------------------------------------------------------
__global__ __launch_bounds__(256) void qproj_part(
    const float* __restrict__ x, const float* __restrict__ y,
    const float* __restrict__ Wqe, const float* __restrict__ Wqc,
    float* __restrict__ pq, float* __restrict__ pqc,
    unsigned* __restrict__ gcnt, unsigned* __restrict__ gflag) {
  const int blk = blockIdx.x, t = threadIdx.x;
  const int qb = blk >> 3, slice = blk & 7;
  const int h = t >> 7, j = t & 127;
  const int S = slice * 2 + h;   // 0..15 K-subslice of concat(x,y)

  if (slice == 0 && t == 0) { gcnt[qb] = 0u; gflag[qb] = 0u; }

  const float* srcA = (S < 8) ? (x + qb * kD + S * 128)
                              : (y + qb * kD + (S - 8) * 128);
  const float* wA = Wqe + (size_t)(S * 128) * kDE + j;
  float s0 = 0.f, s1 = 0.f, s2 = 0.f, s3 = 0.f;
#pragma unroll 8
  for (int i = 0; i < 128; i += 4) {
    s0 += srcA[i]     * wA[(size_t)(i)     * kDE];
    s1 += srcA[i + 1] * wA[(size_t)(i + 1) * kDE];
    s2 += srcA[i + 2] * wA[(size_t)(i + 2) * kDE];
    s3 += srcA[i + 3] * wA[(size_t)(i + 3) * kDE];
  }
  pq[(qb * 16 + S) * 128 + j] = (s0 + s1) + (s2 + s3);

  const float* srcB = x + qb * kD + S * 64;
  const float* wB = Wqc + (size_t)(S * 64) * kDE + j;
  float c0 = 0.f, c1 = 0.f, c2 = 0.f, c3 = 0.f;
#pragma unroll 8
  for (int i = 0; i < 64; i += 4) {
    c0 += srcB[i]     * wB[(size_t)(i)     * kDE];
    c1 += srcB[i + 1] * wB[(size_t)(i + 1) * kDE];
    c2 += srcB[i + 2] * wB[(size_t)(i + 2) * kDE];
    c3 += srcB[i + 3] * wB[(size_t)(i + 3) * kDE];
  }
  pqc[(qb * 16 + S) * 128 + j] = (c0 + c1) + (c2 + c3);
}

// ---------------------------------------------------------------------------
// Kernel B: scores (R7-verbatim hot loop) with per-block q-reduce prologue
// (16 pq slices, L2-hot, + normalize -> LDS). grid (64, 32), block 256.
// ---------------------------------------------------------------------------
__global__ __launch_bounds__(256) void scores_kernel(
    const float* __restrict__ emK, const float* __restrict__ emS,
    const float* __restrict__ pq, const float* __restrict__ bqe,
    float* __restrict__ sc,
    unsigned int* __restrict__ gcnt, unsigned long long* __restrict__ gcand,
    unsigned int* __restrict__ gflag) {
  const int b = blockIdx.y, chunk = blockIdx.x;
  const int t = threadIdx.x;
  const int wave = t >> 6;
  const int lane = t & 63;
  const int half = lane >> 5;
  const int l32 = lane & 31;

  __shared__ float ql[128];
  __shared__ float redn[2];
  __shared__ unsigned int lcnt;
  __shared__ unsigned int lbase;
  __shared__ unsigned long long lbuf[kLBuf];
  if (t == 0) lcnt = 0u;

  // ---- q reduce + normalize (redundant per block; 8KB L2-hot)
  float aq = 0.f;
  if (t < 128) {
    aq = bqe[t];
#pragma unroll
    for (int S2 = 0; S2 < 16; ++S2) aq += pq[(b * 16 + S2) * 128 + t];
    float sq = aq * aq;
#pragma unroll
    for (int m = 1; m < 64; m <<= 1) sq += __shfl_xor(sq, m);
    if ((t & 63) == 0) redn[t >> 6] = sq;
  }
  __syncthreads();
  if (t < 128) ql[t] = aq * (1.f / sqrtf(redn[0] + redn[1] + 1e-12f));
  __syncthreads();

  const float4 qf = *reinterpret_cast<const float4*>(&ql[l32 * 4]);
  const int rowbase = chunk * 512 + wave * 128;
  const float* Kb = emK + (size_t)b * kM * kDE;
  const float* Sb = emS + (size_t)b * kM;
  float* scb = sc + (size_t)b * kM;

  for (int it = 0; it < 8; ++it) {
    const int A = rowbase + it * 16 + half * 8;
    const float* p = Kb + (size_t)A * kDE + l32 * 4;
    const f4 k0 = __builtin_nontemporal_load((const f4*)(p));
    const f4 k1 = __builtin_nontemporal_load((const f4*)(p + kDE));
    const f4 k2 = __builtin_nontemporal_load((const f4*)(p + 2 * kDE));
    const f4 k3 = __builtin_nontemporal_load((const f4*)(p + 3 * kDE));
    const f4 k4 = __builtin_nontemporal_load((const f4*)(p + 4 * kDE));
    const f4 k5 = __builtin_nontemporal_load((const f4*)(p + 5 * kDE));
    const f4 k6 = __builtin_nontemporal_load((const f4*)(p + 6 * kDE));
    const f4 k7 = __builtin_nontemporal_load((const f4*)(p + 7 * kDE));

    float d0 = fmaf(k0.w, qf.w, fmaf(k0.z, qf.z, fmaf(k0.y, qf.y, k0.x * qf.x)));
    float d1 = fmaf(k1.w, qf.w, fmaf(k1.z, qf.z, fmaf(k1.y, qf.y, k1.x * qf.x)));
    float d2 = fmaf(k2.w, qf.w, fmaf(k2.z, qf.z, fmaf(k2.y, qf.y, k2.x * qf.x)));
    float d3 = fmaf(k3.w, qf.w, fmaf(k3.z, qf.z, fmaf(k3.y, qf.y, k3.x * qf.x)));
    float d4 = fmaf(k4.w, qf.w, fmaf(k4.z, qf.z, fmaf(k4.y, qf.y, k4.x * qf.x)));
    float d5 = fmaf(k5.w, qf.w, fmaf(k5.z, qf.z, fmaf(k5.y, qf.y, k5.x * qf.x)));
    float d6 = fmaf(k6.w, qf.w, fmaf(k6.z, qf.z, fmaf(k6.y, qf.y, k6.x * qf.x)));
    float d7 = fmaf(k7.w, qf.w, fmaf(k7.z, qf.z, fmaf(k7.y, qf.y, k7.x * qf.x)));

    // folded butterfly reduce: lane 4k ends with total for row A+k
    d0 += __shfl_xor(d0, 16); d1 += __shfl_xor(d1, 16);
    d2 += __shfl_xor(d2, 16); d3 += __shfl_xor(d3, 16);
    d4 += __shfl_xor(d4, 16); d5 += __shfl_xor(d5, 16);
    d6 += __shfl_xor(d6, 16); d7 += __shfl_xor(d7, 16);
    float w0 = (l32 & 16) ? d4 : d0;
    float w1 = (l32 & 16) ? d5 : d1;
    float w2 = (l32 & 16) ? d6 : d2;
    float w3 = (l32 & 16) ? d7 : d3;
    w0 += __shfl_xor(w0, 8); w1 += __shfl_xor(w1, 8);
    w2 += __shfl_xor(w2, 8); w3 += __shfl_xor(w3, 8);
    float u0 = (l32 & 8) ? w2 : w0;
    float u1 = (l32 & 8) ? w3 : w1;
    u0 += __shfl_xor(u0, 4); u1 += __shfl_xor(u1, 4);
    float z = (l32 & 4) ? u1 : u0;
    z += __shfl_xor(z, 2);
    z += __shfl_xor(z, 1);

    const float sv = Sb[A + (l32 >> 2)];
    if ((l32 & 3) == 0) {
      const int row = A + (l32 >> 2);
      const float val = (sv > 0.f) ? z : -INFINITY;
      __builtin_nontemporal_store(val, &scb[row]);
      if (val >= kT0) {
        const unsigned pos = atomicAdd(&lcnt, 1u);   // LDS atomic only
        if (pos < (unsigned)kLBuf) lbuf[pos] = pack_key(val, row);
      }
    }
  }
  __syncthreads();

  // one flush per block
  const unsigned c = min(lcnt, (unsigned)kLBuf);
  if (t == 0) {
    lbase = atomicAdd(&gcnt[b], c);
    if (lcnt > (unsigned)kLBuf) atomicOr(&gflag[b], 1u);
  }
  __syncthreads();
  const unsigned base = lbase;
  for (unsigned i = t; i < c; i += 256) {
    const unsigned pos = base + i;
    if (pos < (unsigned)kCap) gcand[(size_t)b * kCap + pos] = lbuf[i];
  }
}

// ---------------------------------------------------------------------------
// Kernel C: finish (R12-verbatim) with qc reduced from pqc in prologue.
// grid 32, block 512.
// ---------------------------------------------------------------------------
__global__ __launch_bounds__(512) void finish_kernel(
    const float* __restrict__ sc, const unsigned int* __restrict__ gcnt,
    const unsigned long long* __restrict__ gcand,
    const unsigned int* __restrict__ gflag,
    const float* __restrict__ emV,
    const float* __restrict__ pqc, const float* __restrict__ bqc,
    const float* __restrict__ lng, const float* __restrict__ lnb,
    const float* __restrict__ f1w, const float* __restrict__ f1b,
    const float* __restrict__ f2w, const float* __restrict__ f2b,
    const float* __restrict__ Wo, const float* __restrict__ Wob,
    float* __restrict__ out) {
  const int b = blockIdx.x, t = threadIdx.x;
  const int wave = t >> 6, lane = t & 63;

  __shared__ unsigned long long ck[kCap];
  __shared__ int nS;
  __shared__ float outvS[32];
  __shared__ int outiS[32];
  __shared__ float Vt[32][128];
  __shared__ float qcl[128];
  __shared__ float wgt[32];
  __shared__ float hS[128];
  __shared__ float y1S[512];
  __shared__ float p2S[4][128];
  __shared__ float o2S[128];
  __shared__ float redA[2];
  __shared__ float redB[2];

  const unsigned cnt = gcnt[b];
  const unsigned flag = gflag[b];
  const float* scb = sc + (size_t)b * kM;
  if (t < 128) {
    float cc = bqc[t];
#pragma unroll
    for (int S2 = 0; S2 < 16; ++S2) cc += pqc[(b * 16 + S2) * 128 + t];
    qcl[t] = cc;
  }
  if (t < 32) { outvS[t] = -INFINITY; outiS[t] = 0; }

  if (flag == 0u && cnt >= 32u && cnt <= (unsigned)kCap) {
    for (unsigned i = t; i < cnt; i += 512)
      ck[i] = gcand[(size_t)b * kCap + i];
    if (t == 0) nS = (int)cnt;
  } else {
    __shared__ unsigned int shist[256];
    __shared__ int Bsh;
    __shared__ unsigned int cnt2;
    if (t < 256) shist[t] = 0u;
    if (t == 0) { Bsh = 0; cnt2 = 0u; }
    __syncthreads();
    for (int i = t; i < kM; i += 512)
      atomicAdd(&shist[score_bin(scb[i])], 1u);
    __syncthreads();
    for (int off = 1; off < 256; off <<= 1) {
      unsigned v = 0;
      if (t < 256) {
        v = shist[t];
        if (t + off < 256) v += shist[t + off];
      }
      __syncthreads();
      if (t < 256) shist[t] = v;
      __syncthreads();
    }
    if (t < 256 && shist[t] >= 32u) atomicMax(&Bsh, t);
    __syncthreads();
    const int B = Bsh;
    for (int i = t; i < kM; i += 512) {
      const float s = scb[i];
      if (score_bin(s) >= B) {
        const unsigned pos = atomicAdd(&cnt2, 1u);
        if (pos < (unsigned)kCap) ck[pos] = pack_key(s, i);
      }
    }
    __syncthreads();
    if (t == 0) nS = (int)min(cnt2, (unsigned)kCap);
  }
  __syncthreads();
  const int n = nS;

  unsigned long long mykey0 = 0, mykey1 = 0, mykey2 = 0, mykey3 = 0;
  if (t < n) mykey0 = ck[t];
  if (t + 512 < n) mykey1 = ck[t + 512];
  if (t + 1024 < n) mykey2 = ck[t + 1024];
  if (t + 1536 < n) mykey3 = ck[t + 1536];
  int r0 = 0, r1 = 0, r2 = 0, r3 = 0;
  for (int i = 0; i < n; ++i) {
    const unsigned long long o = ck[i];
    r0 += (o > mykey0);
    r1 += (o > mykey1);
    r2 += (o > mykey2);
    r3 += (o > mykey3);
  }
  auto emit = [&](unsigned long long key, int rank, int slot) {
    if (slot < n && rank < 32) {
      const unsigned mono = (unsigned)(key >> 32);
      const unsigned u = (mono & 0x80000000u) ? (mono & 0x7fffffffu) : ~mono;
      outvS[rank] = __uint_as_float(u);
      outiS[rank] = (int)(~(unsigned)key);
    }
  };
  emit(mykey0, r0, t);
  emit(mykey1, r1, t + 512);
  emit(mykey2, r2, t + 1024);
  emit(mykey3, r3, t + 1536);
  __syncthreads();

  const float* Vb = emV + (size_t)b * kM * kDE;
#pragma unroll
  for (int e = t; e < 32 * 128; e += 512) {
    const int r = e >> 7, ccol = e & 127;
    Vt[r][ccol] = Vb[(size_t)outiS[r] * kDE + ccol];
  }
  __syncthreads();

#pragma unroll
  for (int kk2 = 0; kk2 < 4; ++kk2) {
    const int k = wave * 4 + kk2;
    float p = Vt[k][2 * lane] * qcl[2 * lane] + Vt[k][2 * lane + 1] * qcl[2 * lane + 1];
#pragma unroll
    for (int m = 1; m < 64; m <<= 1) p += __shfl_xor(p, m);
    if (lane == 0) {
      const float tv = outvS[k];
      wgt[k] = (tv == -INFINITY) ? -INFINITY : fmaf(p, 0.08838834764831845f, tv);
    }
  }
  __syncthreads();

  if (t < 32) {
    const float lg = wgt[t];
    float mx = lg;
#pragma unroll
    for (int m = 1; m < 32; m <<= 1) mx = fmaxf(mx, __shfl_xor(mx, m));
    float e = (mx == -INFINITY || lg == -INFINITY) ? 0.f : __expf(lg - mx);
    float ssum = e;
#pragma unroll
    for (int m = 1; m < 32; m <<= 1) ssum += __shfl_xor(ssum, m);
    wgt[t] = (ssum > 0.f) ? e / ssum : 0.f;
  }
  __syncthreads();

  float od = 0.f;
  if (t < 128) {
#pragma unroll 8
    for (int k = 0; k < 32; ++k) od += wgt[k] * Vt[k][t];
  }
  float s1 = (t < 128) ? od : 0.f;
  float s2 = (t < 128) ? od * od : 0.f;
#pragma unroll
  for (int m = 1; m < 64; m <<= 1) {
    s1 += __shfl_xor(s1, m);
    s2 += __shfl_xor(s2, m);
  }
  if (lane == 0 && wave < 2) { redA[wave] = s1; redB[wave] = s2; }
  __syncthreads();
  const float sum1 = redA[0] + redA[1];
  const float sum2 = redB[0] + redB[1];
  const float mu = sum1 * (1.f / 128.f);
  const float var = sum2 * (1.f / 128.f) - mu * mu;
  const float rstd = 1.f / sqrtf(var + 1e-5f);
  if (t < 128) hS[t] = (od - mu) * rstd * lng[t] + lnb[t];
  __syncthreads();

  {
    float acc = f1b[t];
#pragma unroll 8
    for (int d = 0; d < 128; ++d) acc += hS[d] * f1w[(size_t)d * 512 + t];
    y1S[t] = 0.5f * acc * (1.f + erff(acc * 0.7071067811865476f));
  }
  __syncthreads();

  {
    const int g = t >> 7, ccol = t & 127;
    float acc = 0.f;
#pragma unroll 8
    for (int jj = 0; jj < 128; ++jj)
      acc += y1S[g * 128 + jj] * f2w[(size_t)(g * 128 + jj) * 128 + ccol];
    p2S[g][ccol] = acc;
  }
  __syncthreads();
  if (t < 128)
    o2S[t] = od + f2b[t] + ((p2S[0][t] + p2S[1][t]) + (p2S[2][t] + p2S[3][t]));
  __syncthreads();

  float acc0 = Wob[t], acc1 = Wob[t + 512];
#pragma unroll 8
  for (int d = 0; d < 128; ++d) {
    const float hv = o2S[d];
    acc0 += hv * Wo[(size_t)d * kD + t];
    acc1 += hv * Wo[(size_t)d * kD + t + 512];
  }
  out[(size_t)b * kD + t] = acc0;
  out[(size_t)b * kD + t + 512] = acc1;
}

// ---------------------------------------------------------------------------
extern "C" void kernel_launch(void* const* d_in, const int* in_sizes, int n_in,
                              void* d_out, int out_size, void* d_ws, size_t ws_size,
                              hipStream_t stream) {
  const float* x   = (const float*)d_in[0];
  const float* y   = (const float*)d_in[1];
  const float* emK = (const float*)d_in[2];
  const float* emV = (const float*)d_in[3];
  const float* emS = (const float*)d_in[4];
  const float* Wqe = (const float*)d_in[5];
  const float* bqe = (const float*)d_in[6];
  const float* Wqc = (const float*)d_in[7];
  const float* bqc = (const float*)d_in[8];
  const float* Wo  = (const float*)d_in[9];
  const float* Wob = (const float*)d_in[10];
  const float* lng = (const float*)d_in[11];
  const float* lnb = (const float*)d_in[12];
  const float* f1w = (const float*)d_in[13];
  const float* f1b = (const float*)d_in[14];
  const float* f2w = (const float*)d_in[15];
  const float* f2b = (const float*)d_in[16];
  float* out = (float*)d_out;

  float* ws = (float*)d_ws;
  float* pq  = ws;                                  // 65536 f
  float* pqc = ws + 65536;                          // 65536 f
  float* sc  = ws + 131072;                         // 1048576 f
  unsigned* gcnt  = (unsigned*)(ws + 1179648);      // 32
  unsigned* gflag = gcnt + 32;                      // 32
  unsigned long long* gcand =
      (unsigned long long*)(ws + 1179776);          // 32*2048 u64 (8B-aligned)

  hipLaunchKernelGGL(qproj_part, dim3(256), dim3(256), 0, stream,
                     x, y, Wqe, Wqc, pq, pqc, gcnt, gflag);
  hipLaunchKernelGGL(scores_kernel, dim3(64, 32), dim3(256), 0, stream,
                     emK, emS, pq, bqe, sc, gcnt, gcand, gflag);
  hipLaunchKernelGGL(finish_kernel, dim3(32), dim3(512), 0, stream,
                     sc, gcnt, gcand, gflag, emV, pqc, bqc, lng, lnb,
                     f1w, f1b, f2w, f2b, Wo, Wob, out);
}